// Round 1
// baseline (602.675 us; speedup 1.0000x reference)
//
#include <hip/hip_runtime.h>

// GCN: h' = relu(A @ (h @ W) + b) x3, last layer no relu.
// Strategy: build dst-CSR per call (hist + scan + counting sort), then per
// layer: fp32 LDS-tiled GEMM (support = h@W), then per-node gather-accumulate
// (no atomics in the hot loop).

constexpr int NN = 50000;          // nodes
constexpr int NE = 800000;         // edges
constexpr int SCAN_B = (NN + 1023) / 1024;   // 49

// ---------------- CSR build ----------------

__global__ void k_hist(const int* __restrict__ dst, int* __restrict__ cnt) {
    int i = blockIdx.x * blockDim.x + threadIdx.x;
    if (i < NE) atomicAdd(&cnt[dst[i]], 1);
}

__global__ __launch_bounds__(1024) void k_scan_local(
        const int* __restrict__ cnt, int* __restrict__ rowp,
        int* __restrict__ bsum) {
    __shared__ int sh[1024];
    int t = threadIdx.x;
    int idx = blockIdx.x * 1024 + t;
    int v = (idx < NN) ? cnt[idx] : 0;
    sh[t] = v;
    __syncthreads();
    for (int off = 1; off < 1024; off <<= 1) {
        int add = (t >= off) ? sh[t - off] : 0;
        __syncthreads();
        sh[t] += add;
        __syncthreads();
    }
    if (idx < NN) rowp[idx] = sh[t] - v;     // local exclusive
    if (t == 1023) bsum[blockIdx.x] = sh[1023];
}

__global__ void k_scan_bsum(const int* __restrict__ bsum, int* __restrict__ boff,
                            int* __restrict__ rowp) {
    if (threadIdx.x == 0 && blockIdx.x == 0) {
        int run = 0;
        for (int i = 0; i < SCAN_B; ++i) { boff[i] = run; run += bsum[i]; }
        rowp[NN] = run;   // == NE
    }
}

__global__ __launch_bounds__(1024) void k_scan_add(
        int* __restrict__ rowp, int* __restrict__ fill,
        const int* __restrict__ boff) {
    int idx = blockIdx.x * 1024 + threadIdx.x;
    if (idx < NN) {
        int v = rowp[idx] + boff[blockIdx.x];
        rowp[idx] = v;
        fill[idx] = v;
    }
}

__global__ void k_scatter(const int* __restrict__ src, const int* __restrict__ dst,
                          const float* __restrict__ w,
                          int* __restrict__ fill,
                          int* __restrict__ src_s, float* __restrict__ w_s) {
    int i = blockIdx.x * blockDim.x + threadIdx.x;
    if (i < NE) {
        int d = dst[i];
        int pos = atomicAdd(&fill[d], 1);
        src_s[pos] = src[i];
        w_s[pos]   = w[i];
    }
}

// ---------------- GEMM: C[M x N] = A[M x 128] @ W[128 x N] ----------------
// 256 threads = 16 rowgroups x 16 colgroups; thread tile 4 rows x (N/16) cols.
// W staged in LDS, stride padded +4 floats to break bank-conflict stride.

template<int N>
__global__ __launch_bounds__(256) void k_gemm(
        const float* __restrict__ A, const float* __restrict__ W,
        float* __restrict__ C, int M) {
    constexpr int TC  = N / 16;      // cols per thread: 8 (N=128) or 4 (N=64)
    constexpr int PAD = N + 4;
    __shared__ float sW[128 * PAD];

    int tid = threadIdx.x;
    for (int idx = tid; idx < 128 * N; idx += 256) {
        int k = idx / N, j = idx - k * N;
        sW[k * PAD + j] = W[idx];
    }
    __syncthreads();

    int rowg = tid >> 4;             // 0..15
    int colg = tid & 15;             // 0..15
    int r0 = blockIdx.x * 64 + rowg * 4;
    int j0 = colg * TC;

    float acc[4][TC];
#pragma unroll
    for (int r = 0; r < 4; ++r)
#pragma unroll
        for (int j = 0; j < TC; ++j) acc[r][j] = 0.f;

    for (int k0 = 0; k0 < 128; k0 += 4) {
        float areg[4][4];
#pragma unroll
        for (int r = 0; r < 4; ++r) {
            int row = r0 + r;
            float4 v = (row < M) ? *(const float4*)&A[(size_t)row * 128 + k0]
                                 : make_float4(0.f, 0.f, 0.f, 0.f);
            areg[r][0] = v.x; areg[r][1] = v.y; areg[r][2] = v.z; areg[r][3] = v.w;
        }
#pragma unroll
        for (int kk = 0; kk < 4; ++kk) {
            float wv[TC];
#pragma unroll
            for (int j = 0; j < TC; ++j) wv[j] = sW[(k0 + kk) * PAD + j0 + j];
#pragma unroll
            for (int r = 0; r < 4; ++r)
#pragma unroll
                for (int j = 0; j < TC; ++j)
                    acc[r][j] = fmaf(areg[r][kk], wv[j], acc[r][j]);
        }
    }

#pragma unroll
    for (int r = 0; r < 4; ++r) {
        int row = r0 + r;
        if (row < M) {
#pragma unroll
            for (int j = 0; j < TC; ++j) C[(size_t)row * N + j0 + j] = acc[r][j];
        }
    }
}

// ---------------- Aggregate: out[n] = act(sum_e w_e * sup[src_e] + b) -------
// One block per node, one thread per output column. Edge list is CSR-sorted
// so indices are block-uniform (scalar loads) and each edge read is one
// coalesced 512B (D=128) / 256B (D=64) row.

template<int D, bool RELU>
__global__ __launch_bounds__(128) void k_agg(
        const float* __restrict__ sup, const int* __restrict__ rowp,
        const int* __restrict__ src_s, const float* __restrict__ w_s,
        const float* __restrict__ bias, float* __restrict__ out) {
    int n = blockIdx.x;
    int t = threadIdx.x;             // 0..D-1
    int beg = rowp[n], end = rowp[n + 1];
    float acc = 0.f;
    int e = beg;
    for (; e + 4 <= end; e += 4) {
        int   s0 = src_s[e],   s1 = src_s[e+1], s2 = src_s[e+2], s3 = src_s[e+3];
        float w0 = w_s[e],     w1 = w_s[e+1],   w2 = w_s[e+2],   w3 = w_s[e+3];
        float v0 = sup[(size_t)s0 * D + t];
        float v1 = sup[(size_t)s1 * D + t];
        float v2 = sup[(size_t)s2 * D + t];
        float v3 = sup[(size_t)s3 * D + t];
        acc += w0 * v0 + w1 * v1 + w2 * v2 + w3 * v3;
    }
    for (; e < end; ++e) acc += w_s[e] * sup[(size_t)src_s[e] * D + t];
    acc += bias[t];
    if (RELU) acc = fmaxf(acc, 0.f);
    out[(size_t)n * D + t] = acc;
}

// ---------------- launch ----------------

extern "C" void kernel_launch(void* const* d_in, const int* in_sizes, int n_in,
                              void* d_out, int out_size, void* d_ws, size_t ws_size,
                              hipStream_t stream) {
    (void)in_sizes; (void)n_in; (void)out_size; (void)ws_size;

    const float* x    = (const float*)d_in[0];
    const int*   esrc = (const int*)d_in[1];
    const int*   edst = (const int*)d_in[2];
    const float* ew   = (const float*)d_in[3];
    const float* W0   = (const float*)d_in[4];
    const float* b0   = (const float*)d_in[5];
    const float* W1   = (const float*)d_in[6];
    const float* b1   = (const float*)d_in[7];
    const float* W2   = (const float*)d_in[8];
    const float* b2   = (const float*)d_in[9];
    const float* W3   = (const float*)d_in[10];
    const float* b3   = (const float*)d_in[11];

    char* p = (char*)d_ws;
    auto alloc = [&](size_t bytes) {
        char* r = p;
        p += (bytes + 511) & ~size_t(511);
        return r;
    };
    int*   cnt  = (int*)  alloc((size_t)NN * 4);
    int*   rowp = (int*)  alloc((size_t)(NN + 1) * 4);
    int*   fill = (int*)  alloc((size_t)NN * 4);
    int*   bsum = (int*)  alloc((size_t)SCAN_B * 4);
    int*   boff = (int*)  alloc((size_t)SCAN_B * 4);
    int*   srcs = (int*)  alloc((size_t)NE * 4);
    float* wsrt = (float*)alloc((size_t)NE * 4);
    float* bufA = (float*)alloc((size_t)NN * 128 * 4);
    float* bufB = (float*)alloc((size_t)NN * 128 * 4);

    // --- CSR build (once per call, reused by all 4 layers) ---
    hipMemsetAsync(cnt, 0, (size_t)NN * 4, stream);
    k_hist<<<(NE + 255) / 256, 256, 0, stream>>>(edst, cnt);
    k_scan_local<<<SCAN_B, 1024, 0, stream>>>(cnt, rowp, bsum);
    k_scan_bsum<<<1, 64, 0, stream>>>(bsum, boff, rowp);
    k_scan_add<<<SCAN_B, 1024, 0, stream>>>(rowp, fill, boff);
    k_scatter<<<(NE + 255) / 256, 256, 0, stream>>>(esrc, edst, ew, fill, srcs, wsrt);

    const int gemm_grid = (NN + 63) / 64;   // 782

    // --- layer 0: x(128) -> 128, relu ---
    k_gemm<128><<<gemm_grid, 256, 0, stream>>>(x, W0, bufB, NN);
    k_agg<128, true><<<NN, 128, 0, stream>>>(bufB, rowp, srcs, wsrt, b0, bufA);

    // --- layer 1: 128 -> 128, relu ---
    k_gemm<128><<<gemm_grid, 256, 0, stream>>>(bufA, W1, bufB, NN);
    k_agg<128, true><<<NN, 128, 0, stream>>>(bufB, rowp, srcs, wsrt, b1, bufA);

    // --- layer 2: 128 -> 128, relu ---
    k_gemm<128><<<gemm_grid, 256, 0, stream>>>(bufA, W2, bufB, NN);
    k_agg<128, true><<<NN, 128, 0, stream>>>(bufB, rowp, srcs, wsrt, b2, bufA);

    // --- layer 3: 128 -> 64, no relu ---
    k_gemm<64><<<gemm_grid, 256, 0, stream>>>(bufA, W3, bufB, NN);
    k_agg<64, false><<<NN, 64, 0, stream>>>(bufB, rowp, srcs, wsrt, b3, (float*)d_out);
}

// Round 2
// 523.130 us; speedup vs baseline: 1.1521x; 1.1521x over previous
//
#include <hip/hip_runtime.h>

// GCN: h' = relu(A @ (h @ W) + b) x3, last layer no relu.
// CSR build per call (hist + scan + counting sort), then per layer:
// fp32 K-chunked LDS GEMM (support = h@W), then per-node gather-accumulate.

constexpr int NN = 50000;          // nodes
constexpr int NE = 800000;         // edges
constexpr int SCAN_B = (NN + 1023) / 1024;   // 49

// ---------------- CSR build ----------------

__global__ void k_hist(const int* __restrict__ dst, int* __restrict__ cnt) {
    int i = blockIdx.x * blockDim.x + threadIdx.x;
    if (i < NE) atomicAdd(&cnt[dst[i]], 1);
}

__global__ __launch_bounds__(1024) void k_scan_local(
        const int* __restrict__ cnt, int* __restrict__ rowp,
        int* __restrict__ bsum) {
    __shared__ int sh[1024];
    int t = threadIdx.x;
    int idx = blockIdx.x * 1024 + t;
    int v = (idx < NN) ? cnt[idx] : 0;
    sh[t] = v;
    __syncthreads();
    for (int off = 1; off < 1024; off <<= 1) {
        int add = (t >= off) ? sh[t - off] : 0;
        __syncthreads();
        sh[t] += add;
        __syncthreads();
    }
    if (idx < NN) rowp[idx] = sh[t] - v;     // local exclusive
    if (t == 1023) bsum[blockIdx.x] = sh[1023];
}

__global__ void k_scan_bsum(const int* __restrict__ bsum, int* __restrict__ boff,
                            int* __restrict__ rowp) {
    if (threadIdx.x == 0 && blockIdx.x == 0) {
        int run = 0;
        for (int i = 0; i < SCAN_B; ++i) { boff[i] = run; run += bsum[i]; }
        rowp[NN] = run;   // == NE
    }
}

__global__ __launch_bounds__(1024) void k_scan_add(
        int* __restrict__ rowp, int* __restrict__ fill,
        const int* __restrict__ boff) {
    int idx = blockIdx.x * 1024 + threadIdx.x;
    if (idx < NN) {
        int v = rowp[idx] + boff[blockIdx.x];
        rowp[idx] = v;
        fill[idx] = v;
    }
}

__global__ void k_scatter(const int* __restrict__ src, const int* __restrict__ dst,
                          const float* __restrict__ w,
                          int* __restrict__ fill,
                          int* __restrict__ src_s, float* __restrict__ w_s) {
    int i = blockIdx.x * blockDim.x + threadIdx.x;
    if (i < NE) {
        int d = dst[i];
        int pos = atomicAdd(&fill[d], 1);
        src_s[pos] = src[i];
        w_s[pos]   = w[i];
    }
}

// ---------------- GEMM: C[M x N] = A[M x 128] @ W[128 x N] ----------------
// M-tile 64, K-chunk 16, 128 threads. Thread tile 8 rows x 8 cols (N=128)
// or 8 rows x 4 cols (N=64), split in quads so every LDS read is a float4
// with 16B lane stride (<=2-way bank aliasing = free). A-tile transposed in
// LDS so a thread's 8 row-values per k are two contiguous float4s.
// LDS = 16*(68+N+4)*4 B = 12.8 KB (N=128) -> high occupancy.

template<int N>
__global__ __launch_bounds__(128, 4) void k_gemm(
        const float* __restrict__ A, const float* __restrict__ W,
        float* __restrict__ C, int M) {
    constexpr int KC   = 16;
    constexpr int PADA = 68;         // 64 + 4, float4-aligned stride
    constexpr int PADW = N + 4;      // 132 or 68, float4-aligned
    constexpr int TC   = (N == 128) ? 8 : 4;
    __shared__ float sAT[KC][PADA];
    __shared__ float sW[KC][PADW];

    const int tid  = threadIdx.x;
    const int rowg = tid >> 4;       // 0..7
    const int colg = tid & 15;       // 0..15
    const int r0   = blockIdx.x * 64;

    float acc[8][TC];
#pragma unroll
    for (int i = 0; i < 8; ++i)
#pragma unroll
        for (int j = 0; j < TC; ++j) acc[i][j] = 0.f;

    for (int k0 = 0; k0 < 128; k0 += KC) {
        // --- stage A-tile (64 rows x 16 k), transposed ---
#pragma unroll
        for (int it = 0; it < 2; ++it) {
            int idx = tid + 128 * it;        // 0..255
            int row = idx >> 2;              // 0..63
            int kq  = idx & 3;               // 0..3
            int gr  = r0 + row; if (gr >= M) gr = M - 1;
            float4 v = *(const float4*)&A[(size_t)gr * 128 + k0 + kq * 4];
            sAT[kq * 4 + 0][row] = v.x;
            sAT[kq * 4 + 1][row] = v.y;
            sAT[kq * 4 + 2][row] = v.z;
            sAT[kq * 4 + 3][row] = v.w;
        }
        // --- stage W chunk (16 k x N cols) ---
#pragma unroll
        for (int it = 0; it < N / 32; ++it) {
            int idx = tid + 128 * it;
            int k   = idx / (N / 4);
            int jq  = idx % (N / 4);
            float4 v = *(const float4*)&W[(size_t)(k0 + k) * N + jq * 4];
            *(float4*)&sW[k][jq * 4] = v;
        }
        __syncthreads();

#pragma unroll
        for (int kk = 0; kk < KC; ++kk) {
            float4 a0 = *(const float4*)&sAT[kk][rowg * 4];
            float4 a1 = *(const float4*)&sAT[kk][32 + rowg * 4];
            float av[8] = {a0.x, a0.y, a0.z, a0.w, a1.x, a1.y, a1.z, a1.w};
            float4 w0 = *(const float4*)&sW[kk][colg * 4];
            float wv[TC];
            wv[0] = w0.x; wv[1] = w0.y; wv[2] = w0.z; wv[3] = w0.w;
            if (N == 128) {
                float4 w1 = *(const float4*)&sW[kk][64 + colg * 4];
                wv[4] = w1.x; wv[5] = w1.y; wv[6] = w1.z; wv[7] = w1.w;
            }
#pragma unroll
            for (int i = 0; i < 8; ++i)
#pragma unroll
                for (int j = 0; j < TC; ++j)
                    acc[i][j] = fmaf(av[i], wv[j], acc[i][j]);
        }
        __syncthreads();
    }

#pragma unroll
    for (int i = 0; i < 8; ++i) {
        int lr  = (i < 4) ? (rowg * 4 + i) : (32 + rowg * 4 + i - 4);
        int row = r0 + lr;
        if (row < M) {
            *(float4*)&C[(size_t)row * N + colg * 4] =
                make_float4(acc[i][0], acc[i][1], acc[i][2], acc[i][3]);
            if (N == 128)
                *(float4*)&C[(size_t)row * N + 64 + colg * 4] =
                    make_float4(acc[i][4], acc[i][5], acc[i][6], acc[i][7]);
        }
    }
}

// ---------------- Aggregate: out[n] = act(sum_e w_e * sup[src_e] + b) -------
// One block per node, one thread per output column. Edge list is CSR-sorted
// so indices are block-uniform (scalar loads) and each edge read is one
// coalesced 512B (D=128) / 256B (D=64) row.

template<int D, bool RELU>
__global__ __launch_bounds__(128) void k_agg(
        const float* __restrict__ sup, const int* __restrict__ rowp,
        const int* __restrict__ src_s, const float* __restrict__ w_s,
        const float* __restrict__ bias, float* __restrict__ out) {
    int n = blockIdx.x;
    int t = threadIdx.x;             // 0..D-1
    int beg = rowp[n], end = rowp[n + 1];
    float acc = 0.f;
    int e = beg;
    for (; e + 4 <= end; e += 4) {
        int   s0 = src_s[e],   s1 = src_s[e+1], s2 = src_s[e+2], s3 = src_s[e+3];
        float w0 = w_s[e],     w1 = w_s[e+1],   w2 = w_s[e+2],   w3 = w_s[e+3];
        float v0 = sup[(size_t)s0 * D + t];
        float v1 = sup[(size_t)s1 * D + t];
        float v2 = sup[(size_t)s2 * D + t];
        float v3 = sup[(size_t)s3 * D + t];
        acc += w0 * v0 + w1 * v1 + w2 * v2 + w3 * v3;
    }
    for (; e < end; ++e) acc += w_s[e] * sup[(size_t)src_s[e] * D + t];
    acc += bias[t];
    if (RELU) acc = fmaxf(acc, 0.f);
    out[(size_t)n * D + t] = acc;
}

// ---------------- launch ----------------

extern "C" void kernel_launch(void* const* d_in, const int* in_sizes, int n_in,
                              void* d_out, int out_size, void* d_ws, size_t ws_size,
                              hipStream_t stream) {
    (void)in_sizes; (void)n_in; (void)out_size; (void)ws_size;

    const float* x    = (const float*)d_in[0];
    const int*   esrc = (const int*)d_in[1];
    const int*   edst = (const int*)d_in[2];
    const float* ew   = (const float*)d_in[3];
    const float* W0   = (const float*)d_in[4];
    const float* b0   = (const float*)d_in[5];
    const float* W1   = (const float*)d_in[6];
    const float* b1   = (const float*)d_in[7];
    const float* W2   = (const float*)d_in[8];
    const float* b2   = (const float*)d_in[9];
    const float* W3   = (const float*)d_in[10];
    const float* b3   = (const float*)d_in[11];

    char* p = (char*)d_ws;
    auto alloc = [&](size_t bytes) {
        char* r = p;
        p += (bytes + 511) & ~size_t(511);
        return r;
    };
    int*   cnt  = (int*)  alloc((size_t)NN * 4);
    int*   rowp = (int*)  alloc((size_t)(NN + 1) * 4);
    int*   fill = (int*)  alloc((size_t)NN * 4);
    int*   bsum = (int*)  alloc((size_t)SCAN_B * 4);
    int*   boff = (int*)  alloc((size_t)SCAN_B * 4);
    int*   srcs = (int*)  alloc((size_t)NE * 4);
    float* wsrt = (float*)alloc((size_t)NE * 4);
    float* bufA = (float*)alloc((size_t)NN * 128 * 4);
    float* bufB = (float*)alloc((size_t)NN * 128 * 4);

    // --- CSR build (once per call, reused by all 4 layers) ---
    hipMemsetAsync(cnt, 0, (size_t)NN * 4, stream);
    k_hist<<<(NE + 255) / 256, 256, 0, stream>>>(edst, cnt);
    k_scan_local<<<SCAN_B, 1024, 0, stream>>>(cnt, rowp, bsum);
    k_scan_bsum<<<1, 64, 0, stream>>>(bsum, boff, rowp);
    k_scan_add<<<SCAN_B, 1024, 0, stream>>>(rowp, fill, boff);
    k_scatter<<<(NE + 255) / 256, 256, 0, stream>>>(esrc, edst, ew, fill, srcs, wsrt);

    const int gemm_grid = (NN + 63) / 64;   // 782

    // --- layer 0: x(128) -> 128, relu ---
    k_gemm<128><<<gemm_grid, 128, 0, stream>>>(x, W0, bufB, NN);
    k_agg<128, true><<<NN, 128, 0, stream>>>(bufB, rowp, srcs, wsrt, b0, bufA);

    // --- layer 1: 128 -> 128, relu ---
    k_gemm<128><<<gemm_grid, 128, 0, stream>>>(bufA, W1, bufB, NN);
    k_agg<128, true><<<NN, 128, 0, stream>>>(bufB, rowp, srcs, wsrt, b1, bufA);

    // --- layer 2: 128 -> 128, relu ---
    k_gemm<128><<<gemm_grid, 128, 0, stream>>>(bufA, W2, bufB, NN);
    k_agg<128, true><<<NN, 128, 0, stream>>>(bufB, rowp, srcs, wsrt, b2, bufA);

    // --- layer 3: 128 -> 64, no relu ---
    k_gemm<64><<<gemm_grid, 128, 0, stream>>>(bufA, W3, bufB, NN);
    k_agg<64, false><<<NN, 64, 0, stream>>>(bufB, rowp, srcs, wsrt, b3, (float*)d_out);
}

// Round 3
// 473.471 us; speedup vs baseline: 1.2729x; 1.1049x over previous
//
#include <hip/hip_runtime.h>

// GCN: h' = relu(A @ (h @ W) + b) x3, last layer no relu.
// CSR build per call (hist + scan + counting sort into packed int2 edges),
// then per layer: fp32 K-chunked LDS GEMM writing bf16 support, then
// per-node wave gather-accumulate (bf16 reads, fp32 accumulate).

constexpr int NN = 50000;          // nodes
constexpr int NE = 800000;         // edges
constexpr int SCAN_B = (NN + 1023) / 1024;   // 49

__device__ inline unsigned short f2bf(float f) {          // RNE fp32->bf16
    unsigned u = __float_as_uint(f);
    u += 0x7fffu + ((u >> 16) & 1u);
    return (unsigned short)(u >> 16);
}
__device__ inline float bflo(unsigned v) { return __uint_as_float(v << 16); }
__device__ inline float bfhi(unsigned v) { return __uint_as_float(v & 0xffff0000u); }

// ---------------- CSR build ----------------

__global__ void k_hist(const int* __restrict__ dst, int* __restrict__ cnt) {
    int i = blockIdx.x * blockDim.x + threadIdx.x;
    if (i < NE) atomicAdd(&cnt[dst[i]], 1);
}

__global__ __launch_bounds__(1024) void k_scan_local(
        const int* __restrict__ cnt, int* __restrict__ rowp,
        int* __restrict__ bsum) {
    __shared__ int sh[1024];
    int t = threadIdx.x;
    int idx = blockIdx.x * 1024 + t;
    int v = (idx < NN) ? cnt[idx] : 0;
    sh[t] = v;
    __syncthreads();
    for (int off = 1; off < 1024; off <<= 1) {
        int add = (t >= off) ? sh[t - off] : 0;
        __syncthreads();
        sh[t] += add;
        __syncthreads();
    }
    if (idx < NN) rowp[idx] = sh[t] - v;     // local exclusive
    if (t == 1023) bsum[blockIdx.x] = sh[1023];
}

__global__ void k_scan_bsum(const int* __restrict__ bsum, int* __restrict__ boff,
                            int* __restrict__ rowp) {
    if (threadIdx.x == 0 && blockIdx.x == 0) {
        int run = 0;
        for (int i = 0; i < SCAN_B; ++i) { boff[i] = run; run += bsum[i]; }
        rowp[NN] = run;   // == NE
    }
}

__global__ __launch_bounds__(1024) void k_scan_add(
        int* __restrict__ rowp, int* __restrict__ fill,
        const int* __restrict__ boff) {
    int idx = blockIdx.x * 1024 + threadIdx.x;
    if (idx < NN) {
        int v = rowp[idx] + boff[blockIdx.x];
        rowp[idx] = v;
        fill[idx] = v;
    }
}

__global__ void k_scatter(const int* __restrict__ src, const int* __restrict__ dst,
                          const float* __restrict__ w,
                          int* __restrict__ fill, int2* __restrict__ es) {
    int i = blockIdx.x * blockDim.x + threadIdx.x;
    if (i < NE) {
        int d = dst[i];
        int pos = atomicAdd(&fill[d], 1);
        es[pos] = make_int2(src[i], __float_as_int(w[i]));   // one 8B store
    }
}

// ---------------- GEMM: C[M x N](bf16) = A[M x 128](f32) @ W[128 x N](f32) --
// M-tile 64, K-chunk 16, 128 threads, per-thread 8x8 (N=128) / 8x4 (N=64).
// All LDS reads are float4 with 16B lane stride (<=2-way aliasing = free).

template<int N>
__global__ __launch_bounds__(128, 4) void k_gemm(
        const float* __restrict__ A, const float* __restrict__ W,
        unsigned short* __restrict__ C, int M) {
    constexpr int KC   = 16;
    constexpr int PADA = 68;
    constexpr int PADW = N + 4;
    constexpr int TC   = (N == 128) ? 8 : 4;
    __shared__ float sAT[KC][PADA];
    __shared__ float sW[KC][PADW];

    const int tid  = threadIdx.x;
    const int rowg = tid >> 4;       // 0..7
    const int colg = tid & 15;       // 0..15
    const int r0   = blockIdx.x * 64;

    float acc[8][TC];
#pragma unroll
    for (int i = 0; i < 8; ++i)
#pragma unroll
        for (int j = 0; j < TC; ++j) acc[i][j] = 0.f;

    for (int k0 = 0; k0 < 128; k0 += KC) {
#pragma unroll
        for (int it = 0; it < 2; ++it) {
            int idx = tid + 128 * it;        // 0..255
            int row = idx >> 2;              // 0..63
            int kq  = idx & 3;               // 0..3
            int gr  = r0 + row; if (gr >= M) gr = M - 1;
            float4 v = *(const float4*)&A[(size_t)gr * 128 + k0 + kq * 4];
            sAT[kq * 4 + 0][row] = v.x;
            sAT[kq * 4 + 1][row] = v.y;
            sAT[kq * 4 + 2][row] = v.z;
            sAT[kq * 4 + 3][row] = v.w;
        }
#pragma unroll
        for (int it = 0; it < N / 32; ++it) {
            int idx = tid + 128 * it;
            int k   = idx / (N / 4);
            int jq  = idx % (N / 4);
            float4 v = *(const float4*)&W[(size_t)(k0 + k) * N + jq * 4];
            *(float4*)&sW[k][jq * 4] = v;
        }
        __syncthreads();

#pragma unroll
        for (int kk = 0; kk < KC; ++kk) {
            float4 a0 = *(const float4*)&sAT[kk][rowg * 4];
            float4 a1 = *(const float4*)&sAT[kk][32 + rowg * 4];
            float av[8] = {a0.x, a0.y, a0.z, a0.w, a1.x, a1.y, a1.z, a1.w};
            float4 w0 = *(const float4*)&sW[kk][colg * 4];
            float wv[TC];
            wv[0] = w0.x; wv[1] = w0.y; wv[2] = w0.z; wv[3] = w0.w;
            if (N == 128) {
                float4 w1 = *(const float4*)&sW[kk][64 + colg * 4];
                wv[4] = w1.x; wv[5] = w1.y; wv[6] = w1.z; wv[7] = w1.w;
            }
#pragma unroll
            for (int i = 0; i < 8; ++i)
#pragma unroll
                for (int j = 0; j < TC; ++j)
                    acc[i][j] = fmaf(av[i], wv[j], acc[i][j]);
        }
        __syncthreads();
    }

#pragma unroll
    for (int i = 0; i < 8; ++i) {
        int lr  = (i < 4) ? (rowg * 4 + i) : (32 + rowg * 4 + i - 4);
        int row = r0 + lr;
        if (row < M) {
            ushort4 o;
            o.x = f2bf(acc[i][0]); o.y = f2bf(acc[i][1]);
            o.z = f2bf(acc[i][2]); o.w = f2bf(acc[i][3]);
            *(ushort4*)&C[(size_t)row * N + colg * 4] = o;
            if (N == 128) {
                ushort4 o2;
                o2.x = f2bf(acc[i][4]); o2.y = f2bf(acc[i][5]);
                o2.z = f2bf(acc[i][6]); o2.w = f2bf(acc[i][7]);
                *(ushort4*)&C[(size_t)row * N + 64 + colg * 4] = o2;
            }
        }
    }
}

// ---------------- Aggregate: out[n] = act(sum_e w_e * sup[src_e] + b) -------
// One wave per node, 2 nodes per 128-thread block. sup is bf16; lane t owns
// cols 2t,2t+1 (D=128) via one packed 4B load -> 256B coalesced row read.

template<bool RELU>
__global__ __launch_bounds__(128) void k_agg128(
        const unsigned short* __restrict__ sup, const int* __restrict__ rowp,
        const int2* __restrict__ es, const float* __restrict__ bias,
        float* __restrict__ out) {
    int n = blockIdx.x * 2 + (threadIdx.x >> 6);
    int t = threadIdx.x & 63;
    int beg = rowp[n], end = rowp[n + 1];
    float a0 = 0.f, a1 = 0.f;
    int e = beg;
    for (; e + 4 <= end; e += 4) {
        int2 m0 = es[e], m1 = es[e+1], m2 = es[e+2], m3 = es[e+3];
        unsigned v0 = *(const unsigned*)&sup[(size_t)m0.x * 128 + t * 2];
        unsigned v1 = *(const unsigned*)&sup[(size_t)m1.x * 128 + t * 2];
        unsigned v2 = *(const unsigned*)&sup[(size_t)m2.x * 128 + t * 2];
        unsigned v3 = *(const unsigned*)&sup[(size_t)m3.x * 128 + t * 2];
        float w0 = __int_as_float(m0.y), w1 = __int_as_float(m1.y);
        float w2 = __int_as_float(m2.y), w3 = __int_as_float(m3.y);
        a0 = fmaf(w0, bflo(v0), a0); a1 = fmaf(w0, bfhi(v0), a1);
        a0 = fmaf(w1, bflo(v1), a0); a1 = fmaf(w1, bfhi(v1), a1);
        a0 = fmaf(w2, bflo(v2), a0); a1 = fmaf(w2, bfhi(v2), a1);
        a0 = fmaf(w3, bflo(v3), a0); a1 = fmaf(w3, bfhi(v3), a1);
    }
    for (; e < end; ++e) {
        int2 m = es[e];
        unsigned v = *(const unsigned*)&sup[(size_t)m.x * 128 + t * 2];
        float w = __int_as_float(m.y);
        a0 = fmaf(w, bflo(v), a0); a1 = fmaf(w, bfhi(v), a1);
    }
    a0 += bias[t * 2];
    a1 += bias[t * 2 + 1];
    if (RELU) { a0 = fmaxf(a0, 0.f); a1 = fmaxf(a1, 0.f); }
    *(float2*)&out[(size_t)n * 128 + t * 2] = make_float2(a0, a1);
}

__global__ __launch_bounds__(128) void k_agg64(
        const unsigned short* __restrict__ sup, const int* __restrict__ rowp,
        const int2* __restrict__ es, const float* __restrict__ bias,
        float* __restrict__ out) {
    int n = blockIdx.x * 2 + (threadIdx.x >> 6);
    int t = threadIdx.x & 63;
    int beg = rowp[n], end = rowp[n + 1];
    float a = 0.f;
    int e = beg;
    for (; e + 4 <= end; e += 4) {
        int2 m0 = es[e], m1 = es[e+1], m2 = es[e+2], m3 = es[e+3];
        float v0 = bflo((unsigned)sup[(size_t)m0.x * 64 + t]);
        float v1 = bflo((unsigned)sup[(size_t)m1.x * 64 + t]);
        float v2 = bflo((unsigned)sup[(size_t)m2.x * 64 + t]);
        float v3 = bflo((unsigned)sup[(size_t)m3.x * 64 + t]);
        a = fmaf(__int_as_float(m0.y), v0, a);
        a = fmaf(__int_as_float(m1.y), v1, a);
        a = fmaf(__int_as_float(m2.y), v2, a);
        a = fmaf(__int_as_float(m3.y), v3, a);
    }
    for (; e < end; ++e) {
        int2 m = es[e];
        a = fmaf(__int_as_float(m.y), bflo((unsigned)sup[(size_t)m.x * 64 + t]), a);
    }
    a += bias[t];
    out[(size_t)n * 64 + t] = a;
}

// ---------------- launch ----------------

extern "C" void kernel_launch(void* const* d_in, const int* in_sizes, int n_in,
                              void* d_out, int out_size, void* d_ws, size_t ws_size,
                              hipStream_t stream) {
    (void)in_sizes; (void)n_in; (void)out_size; (void)ws_size;

    const float* x    = (const float*)d_in[0];
    const int*   esrc = (const int*)d_in[1];
    const int*   edst = (const int*)d_in[2];
    const float* ew   = (const float*)d_in[3];
    const float* W0   = (const float*)d_in[4];
    const float* b0   = (const float*)d_in[5];
    const float* W1   = (const float*)d_in[6];
    const float* b1   = (const float*)d_in[7];
    const float* W2   = (const float*)d_in[8];
    const float* b2   = (const float*)d_in[9];
    const float* W3   = (const float*)d_in[10];
    const float* b3   = (const float*)d_in[11];

    char* p = (char*)d_ws;
    auto alloc = [&](size_t bytes) {
        char* r = p;
        p += (bytes + 511) & ~size_t(511);
        return r;
    };
    int*   cnt  = (int*)  alloc((size_t)NN * 4);
    int*   rowp = (int*)  alloc((size_t)(NN + 1) * 4);
    int*   fill = (int*)  alloc((size_t)NN * 4);
    int*   bsum = (int*)  alloc((size_t)SCAN_B * 4);
    int*   boff = (int*)  alloc((size_t)SCAN_B * 4);
    int2*  es   = (int2*) alloc((size_t)NE * 8);
    unsigned short* bufS = (unsigned short*)alloc((size_t)NN * 128 * 2);
    float* bufH = (float*)alloc((size_t)NN * 128 * 4);

    // --- CSR build (once per call, reused by all 4 layers) ---
    hipMemsetAsync(cnt, 0, (size_t)NN * 4, stream);
    k_hist<<<(NE + 255) / 256, 256, 0, stream>>>(edst, cnt);
    k_scan_local<<<SCAN_B, 1024, 0, stream>>>(cnt, rowp, bsum);
    k_scan_bsum<<<1, 64, 0, stream>>>(bsum, boff, rowp);
    k_scan_add<<<SCAN_B, 1024, 0, stream>>>(rowp, fill, boff);
    k_scatter<<<(NE + 255) / 256, 256, 0, stream>>>(esrc, edst, ew, fill, es);

    const int gemm_grid = (NN + 63) / 64;   // 782
    const int agg_grid  = NN / 2;           // 25000

    // --- layer 0: x(128) -> 128, relu ---
    k_gemm<128><<<gemm_grid, 128, 0, stream>>>(x, W0, bufS, NN);
    k_agg128<true><<<agg_grid, 128, 0, stream>>>(bufS, rowp, es, b0, bufH);

    // --- layer 1: 128 -> 128, relu ---
    k_gemm<128><<<gemm_grid, 128, 0, stream>>>(bufH, W1, bufS, NN);
    k_agg128<true><<<agg_grid, 128, 0, stream>>>(bufS, rowp, es, b1, bufH);

    // --- layer 2: 128 -> 128, relu ---
    k_gemm<128><<<gemm_grid, 128, 0, stream>>>(bufH, W2, bufS, NN);
    k_agg128<true><<<agg_grid, 128, 0, stream>>>(bufS, rowp, es, b2, bufH);

    // --- layer 3: 128 -> 64, no relu ---
    k_gemm<64><<<gemm_grid, 128, 0, stream>>>(bufH, W3, bufS, NN);
    k_agg64<<<agg_grid, 128, 0, stream>>>(bufS, rowp, es, b3, (float*)d_out);
}

// Round 4
// 372.863 us; speedup vs baseline: 1.6163x; 1.2698x over previous
//
#include <hip/hip_runtime.h>

// GCN: h' = relu(A @ (h @ W) + b) x3, last layer no relu.
// Per call: node hist + scan -> rowp; two-phase binned edge sort (bucketed
// partition, then L2-local within-bucket scatter) -> dst-sorted (src,w) list;
// per layer: bf16 MFMA GEMM (support = h@W, fp32 accum), then per-node wave
// gather-accumulate (bf16 reads, fp32 accum, bf16 h output).

constexpr int NN = 50000;          // nodes
constexpr int NE = 800000;         // edges
constexpr int SCAN_B = (NN + 1023) / 1024;   // 49
constexpr int NB = (NN + 127) >> 7;          // 391 buckets (dst >> 7)
constexpr int PART_CHUNK = 4096;             // edges per partition block
constexpr int PART_GRID = (NE + PART_CHUNK - 1) / PART_CHUNK;  // 196

typedef __attribute__((ext_vector_type(8))) short bf16x8;
typedef __attribute__((ext_vector_type(4))) float floatx4;

__device__ inline unsigned short f2bf(float f) {          // RNE fp32->bf16
    unsigned u = __float_as_uint(f);
    u += 0x7fffu + ((u >> 16) & 1u);
    return (unsigned short)(u >> 16);
}
__device__ inline float bflo(unsigned v) { return __uint_as_float(v << 16); }
__device__ inline float bfhi(unsigned v) { return __uint_as_float(v & 0xffff0000u); }

// ---------------- CSR build ----------------

__global__ void k_hist(const int* __restrict__ dst, int* __restrict__ cnt) {
    int i = blockIdx.x * blockDim.x + threadIdx.x;
    if (i < NE) atomicAdd(&cnt[dst[i]], 1);
}

__global__ __launch_bounds__(1024) void k_scan_local(
        const int* __restrict__ cnt, int* __restrict__ rowp,
        int* __restrict__ bsum) {
    __shared__ int sh[1024];
    int t = threadIdx.x;
    int idx = blockIdx.x * 1024 + t;
    int v = (idx < NN) ? cnt[idx] : 0;
    sh[t] = v;
    __syncthreads();
    for (int off = 1; off < 1024; off <<= 1) {
        int add = (t >= off) ? sh[t - off] : 0;
        __syncthreads();
        sh[t] += add;
        __syncthreads();
    }
    if (idx < NN) rowp[idx] = sh[t] - v;     // local exclusive
    if (t == 1023) bsum[blockIdx.x] = sh[1023];
}

__global__ void k_scan_bsum(const int* __restrict__ bsum, int* __restrict__ boff,
                            int* __restrict__ rowp) {
    if (threadIdx.x == 0 && blockIdx.x == 0) {
        int run = 0;
        for (int i = 0; i < SCAN_B; ++i) { boff[i] = run; run += bsum[i]; }
        rowp[NN] = run;   // == NE
    }
}

__global__ __launch_bounds__(1024) void k_scan_add(
        int* __restrict__ rowp, int* __restrict__ fill,
        const int* __restrict__ boff) {
    int idx = blockIdx.x * 1024 + threadIdx.x;
    if (idx < NN) {
        int v = rowp[idx] + boff[blockIdx.x];
        rowp[idx] = v;
        fill[idx] = v;
    }
}

__global__ void k_binit(const int* __restrict__ rowp, int* __restrict__ bfill) {
    int t = threadIdx.x;
    if (t < NB) bfill[t] = rowp[t << 7];
}

// Phase A: partition edges into NB buckets. Block-batched reservation gives
// each block contiguous runs per bucket (~84B) -> low write amplification.
// Payload packs src (16b) | dst&127 (bits 16..22) alongside w.
__global__ __launch_bounds__(256) void k_part(
        const int* __restrict__ src, const int* __restrict__ dst,
        const float* __restrict__ w, int* __restrict__ bfill,
        int2* __restrict__ ep) {
    __shared__ int hist[NB], base[NB], off[NB];
    int tid = threadIdx.x;
    for (int b = tid; b < NB; b += 256) { hist[b] = 0; off[b] = 0; }
    __syncthreads();

    int e0 = blockIdx.x * PART_CHUNK;
    int  sreg[16]; int wreg[16]; short breg[16];
#pragma unroll
    for (int i = 0; i < 16; ++i) {
        int e = e0 + i * 256 + tid;
        if (e < NE) {
            int d = dst[e];
            int b = d >> 7;
            sreg[i] = (src[e] & 0xffff) | ((d & 127) << 16);
            wreg[i] = __float_as_int(w[e]);
            breg[i] = (short)b;
            atomicAdd(&hist[b], 1);
        } else breg[i] = -1;
    }
    __syncthreads();
    for (int b = tid; b < NB; b += 256)
        base[b] = atomicAdd(&bfill[b], hist[b]);
    __syncthreads();
#pragma unroll
    for (int i = 0; i < 16; ++i) {
        if (breg[i] >= 0) {
            int b = breg[i];
            int p = atomicAdd(&off[b], 1);
            ep[base[b] + p] = make_int2(sreg[i], wreg[i]);
        }
    }
}

// Phase B: within-bucket dst sort. All writes land in the bucket's ~16KB
// region of es -> L2-local, full-line evictions.
__global__ __launch_bounds__(256) void k_sort(
        const int2* __restrict__ ep, const int* __restrict__ rowp,
        int* __restrict__ fill, int2* __restrict__ es) {
    int b  = blockIdx.x;
    int n0 = b << 7;
    int n1 = min(n0 + 128, NN);
    int beg = rowp[n0], end = rowp[n1];
    for (int e = beg + threadIdx.x; e < end; e += 256) {
        int2 v = ep[e];
        int d = n0 + ((v.x >> 16) & 127);
        int pos = atomicAdd(&fill[d], 1);
        es[pos] = make_int2(v.x & 0xffff, v.y);
    }
}

// ---------------- dtype conversions ----------------

__global__ void k_cvt_x(const float* __restrict__ x, unsigned short* __restrict__ o,
                        int n4) {
    int i = blockIdx.x * blockDim.x + threadIdx.x;
    if (i < n4) {
        float4 v = *(const float4*)&x[i * 4];
        ushort4 u;
        u.x = f2bf(v.x); u.y = f2bf(v.y); u.z = f2bf(v.z); u.w = f2bf(v.w);
        *(ushort4*)&o[i * 4] = u;
    }
}

// Wt[n][k] = bf16(W[k][n]);   W is [128 x N] fp32.
template<int N>
__global__ void k_cvtW(const float* __restrict__ W, unsigned short* __restrict__ Wt) {
    int n = blockIdx.x;          // 0..N-1
    int k = threadIdx.x;         // 0..127
    Wt[n * 128 + k] = f2bf(W[(size_t)k * N + n]);
}

// ---------------- GEMM (MFMA): C[M x N](bf16) = A[M x 128](bf16) @ W ---------
// 256 threads = 4 waves; wave w owns rows 16w..16w+15 of a 64-row tile.
// K=128 = 4 mfma_f32_16x16x32_bf16 steps. A-frags straight from global
// (row-major bf16 == A-operand layout, 16B/lane). W^T staged in LDS,
// row stride 136 bf16 (pad 8) -> balanced banks for ds_read_b128.

template<int N>
__global__ __launch_bounds__(256) void k_gemm_mfma(
        const unsigned short* __restrict__ A,   // [M][128] bf16
        const unsigned short* __restrict__ Wt,  // [N][128] bf16
        unsigned short* __restrict__ C,         // [M][N] bf16
        int M) {
    constexpr int NT   = N / 16;
    constexpr int WSTR = 136;
    __shared__ unsigned short sWt[N * WSTR];

    const int tid = threadIdx.x;
#pragma unroll
    for (int i = 0; i < N * 16 / 256; ++i) {    // 16B chunks
        int c = i * 256 + tid;
        int row = c >> 4, col = (c & 15) * 8;
        *(uint4*)&sWt[row * WSTR + col] = *(const uint4*)&Wt[row * 128 + col];
    }

    const int wv = tid >> 6;
    const int ln = tid & 63;
    const int m  = ln & 15;
    const int qd = ln >> 4;

    int gr  = blockIdx.x * 64 + wv * 16 + m;
    int grc = (gr < M) ? gr : (M - 1);
    bf16x8 af[4];
#pragma unroll
    for (int s = 0; s < 4; ++s)
        af[s] = *(const bf16x8*)&A[(size_t)grc * 128 + s * 32 + qd * 8];

    __syncthreads();

    floatx4 acc[NT];
#pragma unroll
    for (int c = 0; c < NT; ++c) {
        acc[c] = (floatx4){0.f, 0.f, 0.f, 0.f};
#pragma unroll
        for (int s = 0; s < 4; ++s) {
            bf16x8 bf = *(const bf16x8*)&sWt[(c * 16 + m) * WSTR + s * 32 + qd * 8];
            acc[c] = __builtin_amdgcn_mfma_f32_16x16x32_bf16(af[s], bf, acc[c], 0, 0, 0);
        }
    }

    int row0 = blockIdx.x * 64 + wv * 16 + qd * 4;
#pragma unroll
    for (int c = 0; c < NT; ++c) {
#pragma unroll
        for (int r = 0; r < 4; ++r) {
            int row = row0 + r;
            if (row < M) C[(size_t)row * N + c * 16 + m] = f2bf(acc[c][r]);
        }
    }
}

// ---------------- Aggregate: h'[n] = act(sum_e w_e * sup[src_e] + b) --------
// One wave per node, 2 nodes per 128-thread block. sup bf16; lane t owns
// cols 2t,2t+1 via one packed 4B load -> 256B coalesced row read.
// Output h' written as packed bf16 (for the next MFMA GEMM).

template<bool RELU>
__global__ __launch_bounds__(128) void k_agg128(
        const unsigned short* __restrict__ sup, const int* __restrict__ rowp,
        const int2* __restrict__ es, const float* __restrict__ bias,
        unsigned short* __restrict__ out) {
    int n = blockIdx.x * 2 + (threadIdx.x >> 6);
    int t = threadIdx.x & 63;
    int beg = rowp[n], end = rowp[n + 1];
    float a0 = 0.f, a1 = 0.f;
    int e = beg;
    for (; e + 4 <= end; e += 4) {
        int2 m0 = es[e], m1 = es[e+1], m2 = es[e+2], m3 = es[e+3];
        unsigned v0 = *(const unsigned*)&sup[(size_t)m0.x * 128 + t * 2];
        unsigned v1 = *(const unsigned*)&sup[(size_t)m1.x * 128 + t * 2];
        unsigned v2 = *(const unsigned*)&sup[(size_t)m2.x * 128 + t * 2];
        unsigned v3 = *(const unsigned*)&sup[(size_t)m3.x * 128 + t * 2];
        float w0 = __int_as_float(m0.y), w1 = __int_as_float(m1.y);
        float w2 = __int_as_float(m2.y), w3 = __int_as_float(m3.y);
        a0 = fmaf(w0, bflo(v0), a0); a1 = fmaf(w0, bfhi(v0), a1);
        a0 = fmaf(w1, bflo(v1), a0); a1 = fmaf(w1, bfhi(v1), a1);
        a0 = fmaf(w2, bflo(v2), a0); a1 = fmaf(w2, bfhi(v2), a1);
        a0 = fmaf(w3, bflo(v3), a0); a1 = fmaf(w3, bfhi(v3), a1);
    }
    for (; e < end; ++e) {
        int2 m = es[e];
        unsigned v = *(const unsigned*)&sup[(size_t)m.x * 128 + t * 2];
        float w = __int_as_float(m.y);
        a0 = fmaf(w, bflo(v), a0); a1 = fmaf(w, bfhi(v), a1);
    }
    a0 += bias[t * 2];
    a1 += bias[t * 2 + 1];
    if (RELU) { a0 = fmaxf(a0, 0.f); a1 = fmaxf(a1, 0.f); }
    unsigned pk = (unsigned)f2bf(a0) | ((unsigned)f2bf(a1) << 16);
    *(unsigned*)&out[(size_t)n * 128 + t * 2] = pk;
}

__global__ __launch_bounds__(128) void k_agg64(
        const unsigned short* __restrict__ sup, const int* __restrict__ rowp,
        const int2* __restrict__ es, const float* __restrict__ bias,
        float* __restrict__ out) {
    int n = blockIdx.x * 2 + (threadIdx.x >> 6);
    int t = threadIdx.x & 63;
    int beg = rowp[n], end = rowp[n + 1];
    float a = 0.f;
    int e = beg;
    for (; e + 4 <= end; e += 4) {
        int2 m0 = es[e], m1 = es[e+1], m2 = es[e+2], m3 = es[e+3];
        float v0 = bflo((unsigned)sup[(size_t)m0.x * 64 + t]);
        float v1 = bflo((unsigned)sup[(size_t)m1.x * 64 + t]);
        float v2 = bflo((unsigned)sup[(size_t)m2.x * 64 + t]);
        float v3 = bflo((unsigned)sup[(size_t)m3.x * 64 + t]);
        a = fmaf(__int_as_float(m0.y), v0, a);
        a = fmaf(__int_as_float(m1.y), v1, a);
        a = fmaf(__int_as_float(m2.y), v2, a);
        a = fmaf(__int_as_float(m3.y), v3, a);
    }
    for (; e < end; ++e) {
        int2 m = es[e];
        a = fmaf(__int_as_float(m.y), bflo((unsigned)sup[(size_t)m.x * 64 + t]), a);
    }
    a += bias[t];
    out[(size_t)n * 64 + t] = a;
}

// ---------------- launch ----------------

extern "C" void kernel_launch(void* const* d_in, const int* in_sizes, int n_in,
                              void* d_out, int out_size, void* d_ws, size_t ws_size,
                              hipStream_t stream) {
    (void)in_sizes; (void)n_in; (void)out_size; (void)ws_size;

    const float* x    = (const float*)d_in[0];
    const int*   esrc = (const int*)d_in[1];
    const int*   edst = (const int*)d_in[2];
    const float* ew   = (const float*)d_in[3];
    const float* W0   = (const float*)d_in[4];
    const float* b0   = (const float*)d_in[5];
    const float* W1   = (const float*)d_in[6];
    const float* b1   = (const float*)d_in[7];
    const float* W2   = (const float*)d_in[8];
    const float* b2   = (const float*)d_in[9];
    const float* W3   = (const float*)d_in[10];
    const float* b3   = (const float*)d_in[11];

    char* p = (char*)d_ws;
    auto alloc = [&](size_t bytes) {
        char* r = p;
        p += (bytes + 511) & ~size_t(511);
        return r;
    };
    int*   cnt   = (int*)  alloc((size_t)NN * 4);
    int*   rowp  = (int*)  alloc((size_t)(NN + 1) * 4);
    int*   fill  = (int*)  alloc((size_t)NN * 4);
    int*   bsum  = (int*)  alloc((size_t)SCAN_B * 4);
    int*   boff  = (int*)  alloc((size_t)SCAN_B * 4);
    int*   bfill = (int*)  alloc((size_t)NB * 4);
    int2*  ep    = (int2*) alloc((size_t)NE * 8);
    int2*  es    = (int2*) alloc((size_t)NE * 8);
    unsigned short* hb   = (unsigned short*)alloc((size_t)NN * 128 * 2);
    unsigned short* sup  = (unsigned short*)alloc((size_t)NN * 128 * 2);
    unsigned short* Wt0  = (unsigned short*)alloc((size_t)128 * 128 * 2);
    unsigned short* Wt1  = (unsigned short*)alloc((size_t)128 * 128 * 2);
    unsigned short* Wt2  = (unsigned short*)alloc((size_t)128 * 128 * 2);
    unsigned short* Wt3  = (unsigned short*)alloc((size_t)64 * 128 * 2);

    // --- CSR build ---
    hipMemsetAsync(cnt, 0, (size_t)NN * 4, stream);
    k_hist<<<(NE + 255) / 256, 256, 0, stream>>>(edst, cnt);
    k_scan_local<<<SCAN_B, 1024, 0, stream>>>(cnt, rowp, bsum);
    k_scan_bsum<<<1, 64, 0, stream>>>(bsum, boff, rowp);
    k_scan_add<<<SCAN_B, 1024, 0, stream>>>(rowp, fill, boff);
    k_binit<<<1, 512, 0, stream>>>(rowp, bfill);
    k_part<<<PART_GRID, 256, 0, stream>>>(esrc, edst, ew, bfill, ep);
    k_sort<<<NB, 256, 0, stream>>>(ep, rowp, fill, es);

    // --- dtype prep ---
    k_cvt_x<<<(NN * 128 / 4 + 255) / 256, 256, 0, stream>>>(x, hb, NN * 128 / 4);
    k_cvtW<128><<<128, 128, 0, stream>>>(W0, Wt0);
    k_cvtW<128><<<128, 128, 0, stream>>>(W1, Wt1);
    k_cvtW<128><<<128, 128, 0, stream>>>(W2, Wt2);
    k_cvtW<64><<<64, 128, 0, stream>>>(W3, Wt3);

    const int gemm_grid = (NN + 63) / 64;   // 782
    const int agg_grid  = NN / 2;           // 25000

    // --- layer 0..2: 128 -> 128, relu ---
    k_gemm_mfma<128><<<gemm_grid, 256, 0, stream>>>(hb, Wt0, sup, NN);
    k_agg128<true><<<agg_grid, 128, 0, stream>>>(sup, rowp, es, b0, hb);

    k_gemm_mfma<128><<<gemm_grid, 256, 0, stream>>>(hb, Wt1, sup, NN);
    k_agg128<true><<<agg_grid, 128, 0, stream>>>(sup, rowp, es, b1, hb);

    k_gemm_mfma<128><<<gemm_grid, 256, 0, stream>>>(hb, Wt2, sup, NN);
    k_agg128<true><<<agg_grid, 128, 0, stream>>>(sup, rowp, es, b2, hb);

    // --- layer 3: 128 -> 64, no relu ---
    k_gemm_mfma<64><<<gemm_grid, 256, 0, stream>>>(hb, Wt3, sup, NN);
    k_agg64<<<agg_grid, 128, 0, stream>>>(sup, rowp, es, b3, (float*)d_out);
}

// Round 5
// 309.228 us; speedup vs baseline: 1.9490x; 1.2058x over previous
//
#include <hip/hip_runtime.h>

// GCN: h' = relu(A @ (h @ W) + b) x3, last layer no relu.
// Per call: bucket-level edge binning (bucket hist -> bucket scan -> L2-local
// partition -> within-bucket sort that also emits rowp), then per layer:
// bf16 MFMA GEMM (support = h@W, fp32 accum; layer 0 reads fp32 x directly),
// then per-node wave gather-accumulate (bf16 reads, fp32 accum).

constexpr int NN = 50000;          // nodes
constexpr int NE = 800000;         // edges
constexpr int NB = (NN + 127) >> 7;          // 391 buckets (dst >> 7)
constexpr int PART_CHUNK = 4096;             // edges per partition block
constexpr int PART_GRID = (NE + PART_CHUNK - 1) / PART_CHUNK;  // 196

typedef __attribute__((ext_vector_type(8))) short bf16x8;
typedef __attribute__((ext_vector_type(4))) float floatx4;

__device__ inline unsigned short f2bf(float f) {          // RNE fp32->bf16
    unsigned u = __float_as_uint(f);
    u += 0x7fffu + ((u >> 16) & 1u);
    return (unsigned short)(u >> 16);
}
__device__ inline float bflo(unsigned v) { return __uint_as_float(v << 16); }
__device__ inline float bfhi(unsigned v) { return __uint_as_float(v & 0xffff0000u); }

// ---------------- binned edge sort ----------------

// bucket-level histogram, LDS-aggregated (391 counters)
__global__ __launch_bounds__(256) void k_bhist(
        const int* __restrict__ dst, int* __restrict__ bcnt) {
    __shared__ int h[NB];
    int t = threadIdx.x;
    for (int i = t; i < NB; i += 256) h[i] = 0;
    __syncthreads();
    int e0 = blockIdx.x * PART_CHUNK;
#pragma unroll
    for (int i = 0; i < 16; ++i) {
        int e = e0 + i * 256 + t;
        if (e < NE) atomicAdd(&h[dst[e] >> 7], 1);
    }
    __syncthreads();
    for (int i = t; i < NB; i += 256)
        if (h[i]) atomicAdd(&bcnt[i], h[i]);
}

// exclusive scan over NB bucket counts -> bko (and a working copy bfill)
__global__ __launch_bounds__(512) void k_bscan(
        const int* __restrict__ bcnt, int* __restrict__ bko,
        int* __restrict__ bfill, int* __restrict__ rowp) {
    __shared__ int sh[512];
    int t = threadIdx.x;
    int v = (t < NB) ? bcnt[t] : 0;
    sh[t] = v;
    __syncthreads();
    for (int off = 1; off < 512; off <<= 1) {
        int add = (t >= off) ? sh[t - off] : 0;
        __syncthreads();
        sh[t] += add;
        __syncthreads();
    }
    if (t < NB) { int ex = sh[t] - v; bko[t] = ex; bfill[t] = ex; }
    if (t == NB - 1) bko[NB] = sh[t];     // == NE
    if (t == 0) rowp[NN] = NE;
}

// Phase A: partition edges into NB buckets. Block-batched reservation gives
// each block contiguous runs per bucket -> low write amplification.
// Payload packs src (16b) | dst&127 (bits 16..22) alongside w.
__global__ __launch_bounds__(256) void k_part(
        const int* __restrict__ src, const int* __restrict__ dst,
        const float* __restrict__ w, int* __restrict__ bfill,
        int2* __restrict__ ep) {
    __shared__ int hist[NB], base[NB], off[NB];
    int tid = threadIdx.x;
    for (int b = tid; b < NB; b += 256) { hist[b] = 0; off[b] = 0; }
    __syncthreads();

    int e0 = blockIdx.x * PART_CHUNK;
    int  sreg[16]; int wreg[16]; short breg[16];
#pragma unroll
    for (int i = 0; i < 16; ++i) {
        int e = e0 + i * 256 + tid;
        if (e < NE) {
            int d = dst[e];
            int b = d >> 7;
            sreg[i] = (src[e] & 0xffff) | ((d & 127) << 16);
            wreg[i] = __float_as_int(w[e]);
            breg[i] = (short)b;
            atomicAdd(&hist[b], 1);
        } else breg[i] = -1;
    }
    __syncthreads();
    for (int b = tid; b < NB; b += 256)
        base[b] = atomicAdd(&bfill[b], hist[b]);
    __syncthreads();
#pragma unroll
    for (int i = 0; i < 16; ++i) {
        if (breg[i] >= 0) {
            int b = breg[i];
            int p = atomicAdd(&off[b], 1);
            ep[base[b] + p] = make_int2(sreg[i], wreg[i]);
        }
    }
}

// Phase B: within-bucket dst sort; also computes per-node rowp from an LDS
// per-node histogram + scan. All es writes land in the bucket's ~16KB window.
__global__ __launch_bounds__(256) void k_sort(
        const int2* __restrict__ ep, const int* __restrict__ bko,
        int2* __restrict__ es, int* __restrict__ rowp) {
    __shared__ int cnt[128], base[128], fl[128];
    int b  = blockIdx.x;
    int n0 = b << 7;
    int nn = min(128, NN - n0);
    int t  = threadIdx.x;
    if (t < 128) { cnt[t] = 0; fl[t] = 0; }
    __syncthreads();
    int beg = bko[b], end = bko[b + 1];
    for (int e = beg + t; e < end; e += 256)
        atomicAdd(&cnt[(ep[e].x >> 16) & 127], 1);
    __syncthreads();
    if (t < 128) base[t] = cnt[t];
    __syncthreads();
    for (int off = 1; off < 128; off <<= 1) {
        int add = (t >= off && t < 128) ? base[t - off] : 0;
        __syncthreads();
        if (t < 128) base[t] += add;     // inclusive scan
        __syncthreads();
    }
    if (t < nn) rowp[n0 + t] = beg + base[t] - cnt[t];
    __syncthreads();
    for (int e = beg + t; e < end; e += 256) {
        int2 v = ep[e];
        int d = (v.x >> 16) & 127;
        int pos = beg + base[d] - cnt[d] + atomicAdd(&fl[d], 1);
        es[pos] = make_int2(v.x & 0xffff, v.y);
    }
}

// ---------------- weight transpose+convert (all 4 layers, one kernel) ------

__global__ void k_cvtW_all(
        const float* __restrict__ W0, const float* __restrict__ W1,
        const float* __restrict__ W2, const float* __restrict__ W3,
        unsigned short* __restrict__ T0, unsigned short* __restrict__ T1,
        unsigned short* __restrict__ T2, unsigned short* __restrict__ T3) {
    int b = blockIdx.x;              // 0..447
    const float* W; unsigned short* T; int N, n;
    if (b < 128)      { W = W0; T = T0; N = 128; n = b; }
    else if (b < 256) { W = W1; T = T1; N = 128; n = b - 128; }
    else if (b < 384) { W = W2; T = T2; N = 128; n = b - 256; }
    else              { W = W3; T = T3; N = 64;  n = b - 384; }
    int k = threadIdx.x;             // 0..127
    T[n * 128 + k] = f2bf(W[(size_t)k * N + n]);
}

// ---------------- GEMM (MFMA): C[M x N](bf16) = A[M x 128] @ W --------------
// 256 threads = 4 waves; wave w owns rows 16w..16w+15 of a 64-row tile.
// K=128 = 4 mfma_f32_16x16x32_bf16 steps. A-frags straight from global
// (row-major == A-operand layout); fp32 A converted in-register (layer 0).
// W^T staged in LDS, row stride 136 bf16.

__device__ inline bf16x8 ldA(const unsigned short* A, size_t off) {
    return *(const bf16x8*)&A[off];
}
__device__ inline bf16x8 ldA(const float* A, size_t off) {
    float4 u = *(const float4*)&A[off];
    float4 v = *(const float4*)&A[off + 4];
    bf16x8 r;
    r[0] = (short)f2bf(u.x); r[1] = (short)f2bf(u.y);
    r[2] = (short)f2bf(u.z); r[3] = (short)f2bf(u.w);
    r[4] = (short)f2bf(v.x); r[5] = (short)f2bf(v.y);
    r[6] = (short)f2bf(v.z); r[7] = (short)f2bf(v.w);
    return r;
}

template<int N, typename AT>
__global__ __launch_bounds__(256) void k_gemm_mfma(
        const AT* __restrict__ A,               // [M][128]
        const unsigned short* __restrict__ Wt,  // [N][128] bf16
        unsigned short* __restrict__ C,         // [M][N] bf16
        int M) {
    constexpr int NT   = N / 16;
    constexpr int WSTR = 136;
    __shared__ unsigned short sWt[N * WSTR];

    const int tid = threadIdx.x;
#pragma unroll
    for (int i = 0; i < N * 16 / 256; ++i) {    // 16B chunks
        int c = i * 256 + tid;
        int row = c >> 4, col = (c & 15) * 8;
        *(uint4*)&sWt[row * WSTR + col] = *(const uint4*)&Wt[row * 128 + col];
    }

    const int wv = tid >> 6;
    const int ln = tid & 63;
    const int m  = ln & 15;
    const int qd = ln >> 4;

    int gr  = blockIdx.x * 64 + wv * 16 + m;
    int grc = (gr < M) ? gr : (M - 1);
    bf16x8 af[4];
#pragma unroll
    for (int s = 0; s < 4; ++s)
        af[s] = ldA(A, (size_t)grc * 128 + s * 32 + qd * 8);

    __syncthreads();

    floatx4 acc[NT];
#pragma unroll
    for (int c = 0; c < NT; ++c) {
        acc[c] = (floatx4){0.f, 0.f, 0.f, 0.f};
#pragma unroll
        for (int s = 0; s < 4; ++s) {
            bf16x8 bf = *(const bf16x8*)&sWt[(c * 16 + m) * WSTR + s * 32 + qd * 8];
            acc[c] = __builtin_amdgcn_mfma_f32_16x16x32_bf16(af[s], bf, acc[c], 0, 0, 0);
        }
    }

    int row0 = blockIdx.x * 64 + wv * 16 + qd * 4;
#pragma unroll
    for (int c = 0; c < NT; ++c) {
#pragma unroll
        for (int r = 0; r < 4; ++r) {
            int row = row0 + r;
            if (row < M) C[(size_t)row * N + c * 16 + m] = f2bf(acc[c][r]);
        }
    }
}

// ---------------- Aggregate: h'[n] = act(sum_e w_e * sup[src_e] + b) --------
// One wave per node, 4 nodes per 256-thread block. sup bf16; lane t owns
// cols 2t,2t+1 via one packed 4B load -> 256B coalesced row read. Edge
// metadata read as int4 (2 edges / 16B load), 8-edge unroll.

template<bool RELU>
__global__ __launch_bounds__(256) void k_agg128(
        const unsigned short* __restrict__ sup, const int* __restrict__ rowp,
        const int2* __restrict__ es, const float* __restrict__ bias,
        unsigned short* __restrict__ out) {
    int n = blockIdx.x * 4 + (threadIdx.x >> 6);
    int t = threadIdx.x & 63;
    int beg = rowp[n], end = rowp[n + 1];
    float a0 = 0.f, a1 = 0.f;
    int e = beg;
    auto one = [&](int s, int wbits) {
        unsigned v = *(const unsigned*)&sup[(size_t)s * 128 + t * 2];
        float w = __int_as_float(wbits);
        a0 = fmaf(w, bflo(v), a0); a1 = fmaf(w, bfhi(v), a1);
    };
    if ((e & 1) && e < end) { int2 m = es[e]; one(m.x, m.y); ++e; }
    for (; e + 8 <= end; e += 8) {
        int4 p0 = *(const int4*)&es[e];
        int4 p1 = *(const int4*)&es[e + 2];
        int4 p2 = *(const int4*)&es[e + 4];
        int4 p3 = *(const int4*)&es[e + 6];
        unsigned v0 = *(const unsigned*)&sup[(size_t)p0.x * 128 + t * 2];
        unsigned v1 = *(const unsigned*)&sup[(size_t)p0.z * 128 + t * 2];
        unsigned v2 = *(const unsigned*)&sup[(size_t)p1.x * 128 + t * 2];
        unsigned v3 = *(const unsigned*)&sup[(size_t)p1.z * 128 + t * 2];
        unsigned v4 = *(const unsigned*)&sup[(size_t)p2.x * 128 + t * 2];
        unsigned v5 = *(const unsigned*)&sup[(size_t)p2.z * 128 + t * 2];
        unsigned v6 = *(const unsigned*)&sup[(size_t)p3.x * 128 + t * 2];
        unsigned v7 = *(const unsigned*)&sup[(size_t)p3.z * 128 + t * 2];
        float w0 = __int_as_float(p0.y), w1 = __int_as_float(p0.w);
        float w2 = __int_as_float(p1.y), w3 = __int_as_float(p1.w);
        float w4 = __int_as_float(p2.y), w5 = __int_as_float(p2.w);
        float w6 = __int_as_float(p3.y), w7 = __int_as_float(p3.w);
        a0 = fmaf(w0, bflo(v0), a0); a1 = fmaf(w0, bfhi(v0), a1);
        a0 = fmaf(w1, bflo(v1), a0); a1 = fmaf(w1, bfhi(v1), a1);
        a0 = fmaf(w2, bflo(v2), a0); a1 = fmaf(w2, bfhi(v2), a1);
        a0 = fmaf(w3, bflo(v3), a0); a1 = fmaf(w3, bfhi(v3), a1);
        a0 = fmaf(w4, bflo(v4), a0); a1 = fmaf(w4, bfhi(v4), a1);
        a0 = fmaf(w5, bflo(v5), a0); a1 = fmaf(w5, bfhi(v5), a1);
        a0 = fmaf(w6, bflo(v6), a0); a1 = fmaf(w6, bfhi(v6), a1);
        a0 = fmaf(w7, bflo(v7), a0); a1 = fmaf(w7, bfhi(v7), a1);
    }
    for (; e + 2 <= end; e += 2) {
        int4 p = *(const int4*)&es[e];
        one(p.x, p.y); one(p.z, p.w);
    }
    if (e < end) { int2 m = es[e]; one(m.x, m.y); }
    a0 += bias[t * 2];
    a1 += bias[t * 2 + 1];
    if (RELU) { a0 = fmaxf(a0, 0.f); a1 = fmaxf(a1, 0.f); }
    unsigned pk = (unsigned)f2bf(a0) | ((unsigned)f2bf(a1) << 16);
    *(unsigned*)&out[(size_t)n * 128 + t * 2] = pk;
}

__global__ __launch_bounds__(256) void k_agg64(
        const unsigned short* __restrict__ sup, const int* __restrict__ rowp,
        const int2* __restrict__ es, const float* __restrict__ bias,
        float* __restrict__ out) {
    int n = blockIdx.x * 4 + (threadIdx.x >> 6);
    int t = threadIdx.x & 63;
    int beg = rowp[n], end = rowp[n + 1];
    float a = 0.f;
    int e = beg;
    auto one = [&](int s, int wbits) {
        a = fmaf(__int_as_float(wbits),
                 bflo((unsigned)sup[(size_t)s * 64 + t]), a);
    };
    if ((e & 1) && e < end) { int2 m = es[e]; one(m.x, m.y); ++e; }
    for (; e + 8 <= end; e += 8) {
        int4 p0 = *(const int4*)&es[e];
        int4 p1 = *(const int4*)&es[e + 2];
        int4 p2 = *(const int4*)&es[e + 4];
        int4 p3 = *(const int4*)&es[e + 6];
        float v0 = bflo((unsigned)sup[(size_t)p0.x * 64 + t]);
        float v1 = bflo((unsigned)sup[(size_t)p0.z * 64 + t]);
        float v2 = bflo((unsigned)sup[(size_t)p1.x * 64 + t]);
        float v3 = bflo((unsigned)sup[(size_t)p1.z * 64 + t]);
        float v4 = bflo((unsigned)sup[(size_t)p2.x * 64 + t]);
        float v5 = bflo((unsigned)sup[(size_t)p2.z * 64 + t]);
        float v6 = bflo((unsigned)sup[(size_t)p3.x * 64 + t]);
        float v7 = bflo((unsigned)sup[(size_t)p3.z * 64 + t]);
        a = fmaf(__int_as_float(p0.y), v0, a);
        a = fmaf(__int_as_float(p0.w), v1, a);
        a = fmaf(__int_as_float(p1.y), v2, a);
        a = fmaf(__int_as_float(p1.w), v3, a);
        a = fmaf(__int_as_float(p2.y), v4, a);
        a = fmaf(__int_as_float(p2.w), v5, a);
        a = fmaf(__int_as_float(p3.y), v6, a);
        a = fmaf(__int_as_float(p3.w), v7, a);
    }
    for (; e + 2 <= end; e += 2) {
        int4 p = *(const int4*)&es[e];
        one(p.x, p.y); one(p.z, p.w);
    }
    if (e < end) { int2 m = es[e]; one(m.x, m.y); }
    a += bias[t];
    out[(size_t)n * 64 + t] = a;
}

// ---------------- launch ----------------

extern "C" void kernel_launch(void* const* d_in, const int* in_sizes, int n_in,
                              void* d_out, int out_size, void* d_ws, size_t ws_size,
                              hipStream_t stream) {
    (void)in_sizes; (void)n_in; (void)out_size; (void)ws_size;

    const float* x    = (const float*)d_in[0];
    const int*   esrc = (const int*)d_in[1];
    const int*   edst = (const int*)d_in[2];
    const float* ew   = (const float*)d_in[3];
    const float* W0   = (const float*)d_in[4];
    const float* b0   = (const float*)d_in[5];
    const float* W1   = (const float*)d_in[6];
    const float* b1   = (const float*)d_in[7];
    const float* W2   = (const float*)d_in[8];
    const float* b2   = (const float*)d_in[9];
    const float* W3   = (const float*)d_in[10];
    const float* b3   = (const float*)d_in[11];

    char* p = (char*)d_ws;
    auto alloc = [&](size_t bytes) {
        char* r = p;
        p += (bytes + 511) & ~size_t(511);
        return r;
    };
    int*   bcnt  = (int*)  alloc((size_t)NB * 4);
    int*   bko   = (int*)  alloc((size_t)(NB + 1) * 4);
    int*   bfill = (int*)  alloc((size_t)NB * 4);
    int*   rowp  = (int*)  alloc((size_t)(NN + 1) * 4);
    int2*  ep    = (int2*) alloc((size_t)NE * 8);
    int2*  es    = (int2*) alloc((size_t)NE * 8);
    unsigned short* hb  = (unsigned short*)alloc((size_t)NN * 128 * 2);
    unsigned short* sup = (unsigned short*)alloc((size_t)NN * 128 * 2);
    unsigned short* Wt0 = (unsigned short*)alloc((size_t)128 * 128 * 2);
    unsigned short* Wt1 = (unsigned short*)alloc((size_t)128 * 128 * 2);
    unsigned short* Wt2 = (unsigned short*)alloc((size_t)128 * 128 * 2);
    unsigned short* Wt3 = (unsigned short*)alloc((size_t)64 * 128 * 2);

    // --- binned edge sort + rowp ---
    hipMemsetAsync(bcnt, 0, (size_t)NB * 4, stream);
    k_bhist<<<PART_GRID, 256, 0, stream>>>(edst, bcnt);
    k_bscan<<<1, 512, 0, stream>>>(bcnt, bko, bfill, rowp);
    k_part<<<PART_GRID, 256, 0, stream>>>(esrc, edst, ew, bfill, ep);
    k_sort<<<NB, 256, 0, stream>>>(ep, bko, es, rowp);

    // --- weights ---
    k_cvtW_all<<<448, 128, 0, stream>>>(W0, W1, W2, W3, Wt0, Wt1, Wt2, Wt3);

    const int gemm_grid = (NN + 63) / 64;   // 782
    const int agg_grid  = (NN + 3) / 4;     // 12500

    // --- layer 0: x(fp32,128) -> 128, relu ---
    k_gemm_mfma<128, float><<<gemm_grid, 256, 0, stream>>>(x, Wt0, sup, NN);
    k_agg128<true><<<agg_grid, 256, 0, stream>>>(sup, rowp, es, b0, hb);

    // --- layer 1: 128 -> 128, relu ---
    k_gemm_mfma<128, unsigned short><<<gemm_grid, 256, 0, stream>>>(hb, Wt1, sup, NN);
    k_agg128<true><<<agg_grid, 256, 0, stream>>>(sup, rowp, es, b1, hb);

    // --- layer 2: 128 -> 128, relu ---
    k_gemm_mfma<128, unsigned short><<<gemm_grid, 256, 0, stream>>>(hb, Wt2, sup, NN);
    k_agg128<true><<<agg_grid, 256, 0, stream>>>(sup, rowp, es, b2, hb);

    // --- layer 3: 128 -> 64, no relu ---
    k_gemm_mfma<64, unsigned short><<<gemm_grid, 256, 0, stream>>>(hb, Wt3, sup, NN);
    k_agg64<<<agg_grid, 256, 0, stream>>>(sup, rowp, es, b3, (float*)d_out);
}